// Round 8
// baseline (252.173 us; speedup 1.0000x reference)
//
#include <hip/hip_runtime.h>

#define HSZ 50        // real hidden units
#define TSZ 512       // timesteps
#define NB  16        // batches per workgroup -> 128 wgs, 16 real MFMA cols
#define KPAD 72       // hlds row stride in f16 (144 B): rows 2-way banks (free)
#define NTHR 448      // 7 waves; 2 waves on 3 SIMDs + 1 on the 4th

typedef _Float16 half8  __attribute__((ext_vector_type(8)));
typedef float   floatx4 __attribute__((ext_vector_type(4)));

#define L2E2  2.88539008f      // 2*log2(e)

__device__ __forceinline__ float ex2(float y) { return __builtin_amdgcn_exp2f(y); }
__device__ __forceinline__ float rcpf_(float v){ return __builtin_amdgcn_rcpf(v); }

// R17: same-chain co-scheduling. R12 failed because the 2nd workgroup
// DUPLICATED all issue work; here total per-batch work is constant and the
// chain is spread over 7 waves (2 per SIMD) so one wave's bf-read/trans/
// barrier stalls are filled by its SIMD-mate.
//   NB=16: all 16 MFMA columns are real batches -> per-batch MFMA halves
//     (no mirror columns, no duplicate activation work).
//   Unit-major A-tiles: tile rows r = 4u'+g (u'=unit-in-tile, g=gate).
//     Lane (n,q)'s acc quad for tile j = {i,f,g,o} preacts of unit
//     8w+4j+q, batch n -> ZERO selection cndmasks (R16 spent 16/step).
//   Wave w owns units 8w..8w+7 (2 tiles, 4 MFMAs). Units >= 50 have zero
//     A-rows -> h=0 writes into pad k-slots (harmless). Aug slots k=50
//     (const 1.0) / k=51 (x_{t+1}) are wave 6, tile 0, q=2/3 lanes.
// Kept: K-augmentation (bias k=50, x_t k=51 -> zero C-input), pre-scaled A
// rows (exp2-ready MFMA output), rcp-fused activations (3 rcp/cell),
// scaled-c domain with overflow clamp, 1 barrier/step, f16 h exchange.
__global__ __launch_bounds__(NTHR)
void lstm_umaj(const float* __restrict__ x,
               const float* __restrict__ W_ih,
               const float* __restrict__ W_hh,
               const float* __restrict__ b_ih,
               const float* __restrict__ b_hh,
               const float* __restrict__ W_lin,
               const float* __restrict__ b_lin,
               float* __restrict__ out)
{
    __shared__ float xs[TSZ][NB];                         // x^T [t][b]  (32 KB)
    __shared__ __align__(16) _Float16 hlds[2][16][KPAD];  // aug-h^T dbuf (4.5 KB)

    const int tid = threadIdx.x;
    const int w   = tid >> 6;        // wave 0..6 -> unit group [8w, 8w+8)
    const int ln  = tid & 63;
    const int n   = ln & 15;         // MFMA column = batch
    const int q   = ln >> 4;         // quad -> k-chunk AND unit-in-tile
    const int b0  = blockIdx.x * NB;

    // --- stage x transposed: global [b][t] -> LDS [t][b] (coalesced) ---
    const float* xg = x + (size_t)b0 * TSZ;
    for (int i = tid; i < NB * TSZ; i += NTHR)
        xs[i & (TSZ - 1)][i >> 9] = xg[i];
    // --- init h buffers: zero except k==50 slot = 1.0 (both buffers) ---
    for (int i = tid; i < 2 * 16 * KPAD; i += NTHR)
        ((_Float16*)hlds)[i] = (i % KPAD == 50) ? (_Float16)1.0f : (_Float16)0.0f;

    // --- A fragments, unit-major: tile j row r=n encodes unit 8w+4j+(n>>2),
    //     gate n&3. k<50 -> W_hh ; k==50 -> b_ih+b_hh ; k==51 -> W_ih.
    //     Pre-scale: gates i,f,o -> -log2e ; gate g -> +2*log2e.
    half8 af[2][2];
    {
        const int g  = n & 3;
        const int up = n >> 2;
        const float gs = (g == 2) ? 2.88539008f : -1.44269504f;
#pragma unroll
        for (int j = 0; j < 2; ++j) {
            const int u   = 8 * w + 4 * j + up;
            const int row = g * HSZ + u;
            const bool ok = (u < HSZ);
#pragma unroll
            for (int kt = 0; kt < 2; ++kt) {
#pragma unroll
                for (int jj = 0; jj < 8; ++jj) {
                    const int k = kt * 32 + q * 8 + jj;
                    float v = 0.0f;
                    if (ok) {
                        if (k < HSZ)      v = W_hh[row * HSZ + k];
                        else if (k == 50) v = b_ih[row] + b_hh[row];
                        else if (k == 51) v = W_ih[row];
                    }
                    af[j][kt][jj] = (_Float16)(v * gs);
                }
            }
        }
    }

    float c0 = 0.0f, c1 = 0.0f;      // SCALED cell states (2*log2e*c)
    __syncthreads();                 // xs + hlds base fill ready
    if (tid < NB)                    // x_0 into buffer 0's aug slot
        hlds[0][tid][51] = (_Float16)xs[0][tid];
    __syncthreads();

    const floatx4 zero4 = {0.0f, 0.0f, 0.0f, 0.0f};
    const int u0 = 8 * w + q;        // tile-0 unit; tile-1 unit = u0+4
    _Float16* const hb0 = &hlds[0][n][u0];
    _Float16* const hb1 = &hlds[1][n][u0];
    const bool aug50 = (w == 6) && (q == 2);   // unit 50: const 1.0
    const bool aug51 = (w == 6) && (q == 3);   // unit 51: x_{t+1}

#pragma unroll 2
    for (int t = 0; t < TSZ; ++t) {
        const int rb = t & 1, wb = rb ^ 1;

        // B fragments: hlds[rb][n][k-contiguous]; all 16 cols real batches
        const half8 bf0 = *(const half8*)&hlds[rb][n][q * 8];
        const half8 bf1 = *(const half8*)&hlds[rb][n][32 + q * 8];

        float xnext = 0.0f;
        if (w == 6) xnext = xs[(t + 1) & (TSZ - 1)][n];  // wave-uniform branch

        // 4 MFMAs; cell-0 trans issue overlaps tile-1's second MFMA
        floatx4 a0 = __builtin_amdgcn_mfma_f32_16x16x32_f16(af[0][0], bf0, zero4, 0, 0, 0);
        floatx4 a1 = __builtin_amdgcn_mfma_f32_16x16x32_f16(af[1][0], bf0, zero4, 0, 0, 0);
        a0 = __builtin_amdgcn_mfma_f32_16x16x32_f16(af[0][1], bf1, a0, 0, 0, 0);

        // cell 0: acc quad = {i,f,g,o} directly (unit-major rows)
        const float ei0 = ex2(a0[0]), ef0 = ex2(a0[1]);
        const float eg0 = ex2(a0[2]), eo0 = ex2(a0[3]);

        a1 = __builtin_amdgcn_mfma_f32_16x16x32_f16(af[1][1], bf1, a1, 0, 0, 0);

        const float ig0 = L2E2 * (eg0 - 1.0f) * rcpf_((1.0f + ei0) * (1.0f + eg0));
        const float f0  = rcpf_(1.0f + ef0);
        c0 = fminf(fmaf(f0, c0, ig0), 100.0f);
        const float ec0 = ex2(c0);
        float h0 = (ec0 - 1.0f) * rcpf_((1.0f + eo0) * (1.0f + ec0));

        // cell 1
        const float ei1 = ex2(a1[0]), ef1 = ex2(a1[1]);
        const float eg1 = ex2(a1[2]), eo1 = ex2(a1[3]);
        const float ig1 = L2E2 * (eg1 - 1.0f) * rcpf_((1.0f + ei1) * (1.0f + eg1));
        const float f1  = rcpf_(1.0f + ef1);
        c1 = fminf(fmaf(f1, c1, ig1), 100.0f);
        const float ec1 = ex2(c1);
        float h1 = (ec1 - 1.0f) * rcpf_((1.0f + eo1) * (1.0f + ec1));

        if (aug50) h0 = 1.0f;        // unit 50 slot: augmentation const
        if (aug51) h0 = xnext;       // unit 51 slot: x_{t+1}

        _Float16* const hw = wb ? hb1 : hb0;
        hw[0] = (_Float16)h0;        // col u0     (tile 0's unit)
        hw[4] = (_Float16)h1;        // col u0 + 4 (tile 1's unit)
        __syncthreads();             // h(t) visible for next step's B-read
    }

    // --- epilogue: out[b0+n'] = b_lin + sum_u h_T[u]*W_lin[u]; TSZ even -> buf 0
    if (w == 0 && ln < NB) {
        float acc = b_lin[0];
        for (int u = 0; u < HSZ; ++u)
            acc = fmaf((float)hlds[0][ln][u], W_lin[u], acc);
        out[(size_t)b0 + ln] = acc;
    }
}

extern "C" void kernel_launch(void* const* d_in, const int* in_sizes, int n_in,
                              void* d_out, int out_size, void* d_ws, size_t ws_size,
                              hipStream_t stream) {
    const float* x     = (const float*)d_in[0];
    const float* W_ih  = (const float*)d_in[1];
    const float* W_hh  = (const float*)d_in[2];
    const float* b_ih  = (const float*)d_in[3];
    const float* b_hh  = (const float*)d_in[4];
    const float* W_lin = (const float*)d_in[5];
    const float* b_lin = (const float*)d_in[6];
    float* outp = (float*)d_out;

    const int B = in_sizes[0] / TSZ;   // 2048 -> 128 workgroups of 16 batches
    hipLaunchKernelGGL(lstm_umaj, dim3(B / NB), dim3(NTHR), 0, stream,
                       x, W_ih, W_hh, b_ih, b_hh, W_lin, b_lin, outp);
}